// Round 19
// baseline (765.125 us; speedup 1.0000x reference)
//
#include <hip/hip_runtime.h>
#include <hip/hip_bf16.h>

#define NN 100000
#define EE 1600000
#define DD 128
#define RNG 8        // src ranges for gather L2 locality
#define RSZ 12500    // nodes per range
#define CAPR 16      // csr slots per (node, range)
#define CHK 64       // edge chunks for histogram (1536 blocks = 256 CUs x 6)

typedef __attribute__((ext_vector_type(8))) short bf16x8;
typedef __attribute__((ext_vector_type(4))) float f32x4;
union FB { unsigned u[4]; uint4 u4; bf16x8 v; };

__device__ inline unsigned f2bf(float x){unsigned u=__float_as_uint(x);return (u+0x7fffu+((u>>16)&1u))>>16;}
__device__ inline unsigned bf16pack(float a,float b){return (f2bf(b)<<16)|(f2bf(a)&0xffffu);}
__device__ inline unsigned packsplit(float v){unsigned hb=f2bf(v);float hf=__uint_as_float(hb<<16);unsigned lb=f2bf(v-hf);return (hb<<16)|(lb&0xffffu);}
__device__ inline float bflo(unsigned u){return __uint_as_float(u<<16);}
__device__ inline float bfhi(unsigned u){return __uint_as_float(u&0xffff0000u);}

struct Bufs {
  const float* x;
  const int *s0,*d0,*s1,*d1,*s2,*d2;
  const float *W0,*W1,*W2,*aW,*ab,*aq;
  unsigned *h0,*h1,*h2;      // bf16 h per relation (rs-scaled in gemm0 epilogue)
  unsigned *zb0,*zb1,*zb2;   // bf16 z, h-layout; zb2 overlays h0 (dead after K2)
  ushort *csr0,*csr1;        // csr2 reuses csr0
  int *cursor;               // 3*NN*RNG (+wpart tail)
  float *wpart;              // 4 floats
  float *wblk;               // 3*3125 block partials (no atomics)
  float *rs;                 // 3*NN rsqrt(max(deg_out,1))
  int *histpart;             // overlay on zb0+zb1+csr1 (76.8MB, dead after K0b)
  ushort *fhi,*flo;
  float *out;
};

// ================= K0: hist + zero + prep =================
__global__ __launch_bounds__(256) void k0_kernel(Bufs B) {
  __shared__ unsigned bins[RSZ/2];   // 25 KB
  int b = blockIdx.x;
  if (b < 8*CHK*3) {                 // deg_out hist partials, LDS-privatized
    int range = b & 7, chunk = (b >> 3) & (CHK-1), rel = b >> 9;
    const int* src = rel==0?B.s0: rel==1?B.s1:B.s2;
    for (int i=threadIdx.x;i<RSZ/2;i+=256) bins[i]=0;
    __syncthreads();
    int lo = range*RSZ, e0 = chunk*(EE/CHK);
    for (int e=e0+(int)threadIdx.x; e<e0+EE/CHK; e+=256){
      int v = src[e]-lo;
      if ((unsigned)v<(unsigned)RSZ) atomicAdd(&bins[v>>1], 1u<<((v&1)*16));
    }
    __syncthreads();
    int* outp = B.histpart + ((size_t)(rel*CHK+chunk))*NN + lo;
    for (int i=threadIdx.x;i<RSZ;i+=256) outp[i] = (bins[i>>1]>>((i&1)*16)) & 0xffff;
  } else if (b < 8*CHK*3+587) {      // zero cursors + wpart
    int id = b-8*CHK*3;
    const int Z = 3*NN*RNG + 4;
    int* dst = B.cursor;
#pragma unroll
    for (int k=0;k<4;++k){
      int off = id*4096 + k*1024 + (int)threadIdx.x*4;
      if (off+4 <= Z) *(int4*)(dst+off) = make_int4(0,0,0,0);
      else { for (int j=0;j<4;++j) if (off+j<Z) dst[off+j]=0; }
    }
  } else {                           // prep: W^T hi/lo MFMA fragments
    int m = b - (8*CHK*3+587);
    const float* W = m==0?B.W0: m==1?B.W1: m==2?B.W2: B.aW;
    ushort* ho = B.fhi + (size_t)m*16384;
    ushort* lp = B.flo + (size_t)m*16384;
    for (int idx=threadIdx.x; idx<16384; idx+=256){
      int j=idx&7, lane=(idx>>3)&63, ft=(idx>>9)&7, ks=idx>>12;
      int k = ks*32 + (lane>>4)*8 + j;
      int f = ft*16 + (lane&15);
      float v = W[k*128+f];
      unsigned hb = f2bf(v);
      float hf = __uint_as_float(hb<<16);
      ho[idx]=(ushort)hb; lp[idx]=(ushort)f2bf(v-hf);
    }
  }
}

// ================= K0b: reduce histpart -> rs =================
__global__ __launch_bounds__(256) void reduce_kernel(Bufs B) {
  int tid = blockIdx.x*256 + threadIdx.x;
  if (tid >= 3*NN) return;
  int rel = tid/NN, n = tid-rel*NN;
  const int* p = B.histpart + (size_t)rel*CHK*NN + n;
  int s = 0;
#pragma unroll 16
  for (int c=0;c<CHK;++c) s += p[(size_t)c*NN];
  B.rs[tid] = rsqrtf(fmaxf((float)s, 1.f));
}

// ================= jobs =================
__device__ inline void do_bucket(int id, int rel, const Bufs& B) {
  const int* src = rel==0?B.s0: rel==1?B.s1:B.s2;
  const int* dst = rel==0?B.d0: rel==1?B.d1:B.d2;
  int* cur = B.cursor + (size_t)rel*NN*RNG;
  ushort* csr = (rel==1)? B.csr1 : B.csr0;
  int e0 = id*512;
  for (int e=e0+(int)threadIdx.x; e<e0+512; e+=256){
    int s = src[e], d = dst[e];
    int rg = s / RSZ;
    int pos = atomicAdd(&cur[d*RNG+rg], 1);
    if (pos < CAPR) csr[((size_t)d*RNG+rg)*CAPR + pos] = (ushort)(s - rg*RSZ);
  }
}

// h = (x @ W) * rs  (bf16 packed out), split hi/lo 3-pass MFMA
__device__ inline void do_gemm0(int tile, int rel, const Bufs& B, unsigned (*As)[132]) {
  const uint4* Bhi = (const uint4*)(B.fhi + (size_t)rel*16384);
  const uint4* Blo = (const uint4*)(B.flo + (size_t)rel*16384);
  unsigned* h = rel==0?B.h0: rel==1?B.h1:B.h2;
  int t = threadIdx.x, row0 = tile*32;
  for (int idx=t; idx<32*32; idx+=256){
    int r = idx>>5, c4 = (idx&31)<<2;
    float4 v = *(const float4*)(B.x + (size_t)(row0+r)*DD + c4);
    uint4 pk; pk.x=packsplit(v.x); pk.y=packsplit(v.y); pk.z=packsplit(v.z); pk.w=packsplit(v.w);
    *(uint4*)&As[r][c4] = pk;
  }
  __syncthreads();
  int wv=t>>6, l=t&63, ln=l&15, lk=l>>4;
  int nrow=(wv&1)*16+ln, fh=wv>>1;
  f32x4 acc[4];
#pragma unroll
  for (int i=0;i<4;++i) acc[i] = (f32x4){0.f,0.f,0.f,0.f};
#pragma unroll
  for (int ks=0;ks<4;++ks){
    unsigned u[8];
    int kd = ks*32 + lk*8;
    *(uint4*)&u[0] = *(const uint4*)&As[nrow][kd];
    *(uint4*)&u[4] = *(const uint4*)&As[nrow][kd+4];
    FB bh, bl;
#pragma unroll
    for (int i=0;i<4;++i){
      bh.u[i] = (u[2*i]>>16) | (u[2*i+1]&0xffff0000u);
      bl.u[i] = (u[2*i]&0xffffu) | (u[2*i+1]<<16);
    }
#pragma unroll
    for (int fi=0;fi<4;++fi){
      int ft = fh*4+fi;
      FB wh, wl;
      wh.u4 = Bhi[(ks*8+ft)*64 + l];
      wl.u4 = Blo[(ks*8+ft)*64 + l];
      acc[fi] = __builtin_amdgcn_mfma_f32_16x16x32_bf16(wh.v, bh.v, acc[fi],0,0,0);
      acc[fi] = __builtin_amdgcn_mfma_f32_16x16x32_bf16(wl.v, bh.v, acc[fi],0,0,0);
      acc[fi] = __builtin_amdgcn_mfma_f32_16x16x32_bf16(wh.v, bl.v, acc[fi],0,0,0);
    }
  }
  int node = row0+nrow;
  float sc = B.rs[rel*NN + node];
#pragma unroll
  for (int fi=0;fi<4;++fi){
    int ft = fh*4+fi;
    uint2 o;
    o.x = bf16pack(acc[fi][0]*sc, acc[fi][1]*sc);
    o.y = bf16pack(acc[fi][2]*sc, acc[fi][3]*sc);
    *(uint2*)(h + (size_t)node*64 + ft*8 + lk*2) = o;
  }
}

// gather (R6 shape): 1 node/wave, 4 nodes/block; slot-major over 8 ranges
// for ~8-deep load ILP; h pre-scaled. All rels write bf16 zb.
__device__ inline void do_gather(int id, int rel, const Bufs& B) {
  int node = id*4 + (threadIdx.x>>6);
  int lane = threadIdx.x & 63;
  const int* cur = B.cursor + (size_t)rel*NN*RNG + (size_t)node*RNG;
  const ushort* csr = (rel==1)? B.csr1 : B.csr0;
  const unsigned* h = rel==0?B.h0: rel==1?B.h1:B.h2;
  int cnt[RNG];
  int deg = 0, maxc = 0;
#pragma unroll
  for (int k=0;k<RNG;++k){
    int c = cur[k];
    deg += c;
    c = min(c, CAPR);
    cnt[k] = c;
    maxc = max(maxc, c);
  }
  const ushort* base = csr + (size_t)node*(RNG*CAPR);
  float ax = 0.f, ay = 0.f;
  for (int s=0;s<maxc;++s){
    unsigned u[RNG];
#pragma unroll
    for (int k=0;k<RNG;++k){
      if (s < cnt[k]){
        int idx = k*RSZ + (int)base[k*CAPR + s];
        u[k] = h[(size_t)idx*64 + lane];
      }
    }
#pragma unroll
    for (int k=0;k<RNG;++k){
      if (s < cnt[k]){ ax += bflo(u[k]); ay += bfhi(u[k]); }
    }
  }
  float sc = rsqrtf(fmaxf((float)deg, 1.f));
  unsigned* zb = rel==0?B.zb0: rel==1?B.zb1:B.zb2;
  zb[(size_t)node*64+lane] = bf16pack(ax*sc, ay*sc);
}

// LDS-staged bf16-z semantic GEMM (2 MFMA passes); block partial -> wblk store
__device__ inline void do_g1b(int tile, int rel, const Bufs& B,
                              unsigned (*As)[68], float* red) {
  const unsigned* zb = rel==0?B.zb0: rel==1?B.zb1:B.zb2;
  const uint4* Bhi = (const uint4*)(B.fhi + (size_t)3*16384);
  const uint4* Blo = (const uint4*)(B.flo + (size_t)3*16384);
  int t = threadIdx.x, row0 = tile*32;
  for (int idx=t; idx<32*16; idx+=256){
    int r = idx>>4, c4 = (idx&15)<<2;
    *(uint4*)&As[r][c4] = *(const uint4*)(zb + (size_t)(row0+r)*64 + c4);
  }
  __syncthreads();
  int wv=t>>6, l=t&63, ln=l&15, lk=l>>4;
  int nrow=(wv&1)*16+ln, fh=wv>>1;
  f32x4 acc[4];
#pragma unroll
  for (int i=0;i<4;++i) acc[i] = (f32x4){0.f,0.f,0.f,0.f};
#pragma unroll
  for (int ks=0;ks<4;++ks){
    FB bb; bb.u4 = *(const uint4*)&As[nrow][ks*16 + lk*4];
#pragma unroll
    for (int fi=0;fi<4;++fi){
      int ft = fh*4+fi;
      FB wh, wl;
      wh.u4 = Bhi[(ks*8+ft)*64 + l];
      wl.u4 = Blo[(ks*8+ft)*64 + l];
      acc[fi] = __builtin_amdgcn_mfma_f32_16x16x32_bf16(wh.v, bb.v, acc[fi],0,0,0);
      acc[fi] = __builtin_amdgcn_mfma_f32_16x16x32_bf16(wl.v, bb.v, acc[fi],0,0,0);
    }
  }
  float s = 0.f;
#pragma unroll
  for (int fi=0;fi<4;++fi){
#pragma unroll
    for (int r=0;r<4;++r){
      int f = (fh*4+fi)*16 + lk*4 + r;
      float v = acc[fi][r] + B.ab[f];
      float e = __expf(2.f*v);
      s += (1.f - 2.f/(e+1.f)) * B.aq[f];
    }
  }
#pragma unroll
  for (int m=1;m<64;m<<=1) s += __shfl_xor(s, m);
  if (l==0) red[wv] = s;
  __syncthreads();
  if (t==0) B.wblk[rel*3125 + tile] = red[0]+red[1]+red[2]+red[3];
}

// ===== specialized dispatchers =====

// K1: bucket0(3125) || gemm0 x3(9375)
__global__ __launch_bounds__(256) void megaA(Bufs B) {
  __shared__ unsigned As[32][132];
  const int n0=3125, n1=9375;
  const int tot = n0+n1;
  int b = blockIdx.x;
  long f = ((long)b*n0)/tot;
  if (((long)(b+1)*n0)/tot > f){ do_bucket((int)f, 0, B); return; }
  int g = b-(int)f;
  do_gemm0(g%3125, g/3125, B, As);
}

// K2/K3: gather(25000) || bucket(3125) — 0 LDS, low VGPR
__global__ __launch_bounds__(256) void megaGB(Bufs B, int grel, int brel) {
  const int n0=25000, n1=3125;
  const int tot = n0+n1;
  int b = blockIdx.x;
  long f = ((long)b*n0)/tot;
  if (((long)(b+1)*n0)/tot > f) do_gather((int)f, grel, B);
  else                          do_bucket(b-(int)f, brel, B);
}

// K4: gather2 alone — 0 LDS, low VGPR
__global__ __launch_bounds__(256) void megaG(Bufs B) {
  do_gather(blockIdx.x, 2, B);
}

// K5: g1b x3 (own launch; LDS + MFMA fine when not sharing with gather)
__global__ __launch_bounds__(256) void megaC(Bufs B) {
  __shared__ unsigned As[32][68];
  __shared__ float red[4];
  int b = blockIdx.x;
  if (b < 3125)      do_g1b(b, 0, B, As, red);
  else if (b < 6250) do_g1b(b-3125, 1, B, As, red);
  else               do_g1b(b-6250, 2, B, As, red);
}

// K5b: wreduce — 3 blocks, each sums 3125 block partials -> wpart[rel]
__global__ __launch_bounds__(256) void wreduce_kernel(Bufs B) {
  __shared__ float red[4];
  int rel = blockIdx.x;
  const float* p = B.wblk + rel*3125;
  float s = 0.f;
  for (int i = threadIdx.x; i < 3125; i += 256) s += p[i];
#pragma unroll
  for (int m=1;m<64;m<<=1) s += __shfl_xor(s, m);
  int wv = threadIdx.x>>6, l = threadIdx.x&63;
  if (l==0) red[wv] = s;
  __syncthreads();
  if (threadIdx.x==0) B.wpart[rel] = red[0]+red[1]+red[2]+red[3];
}

// ============ combine: out = b0*zb0 + b1*zb1 + b2*zb2 (f32 out) ============
__global__ __launch_bounds__(256) void combine_kernel(Bufs B) {
  int tid = blockIdx.x*256 + threadIdx.x;   // < NN*64
  float w0 = B.wpart[0]*(1.f/NN), w1 = B.wpart[1]*(1.f/NN), w2 = B.wpart[2]*(1.f/NN);
  float m = fmaxf(w0, fmaxf(w1,w2));
  float e0 = expf(w0-m), e1 = expf(w1-m), e2 = expf(w2-m);
  float inv = 1.f/(e0+e1+e2);
  float b0 = e0*inv, b1 = e1*inv, b2 = e2*inv;
  unsigned u0 = B.zb0[tid], u1 = B.zb1[tid], u2 = B.zb2[tid];
  float2 o;
  o.x = b0*bflo(u0) + b1*bflo(u1) + b2*bflo(u2);
  o.y = b0*bfhi(u0) + b1*bfhi(u1) + b2*bfhi(u2);
  ((float2*)B.out)[tid] = o;
}

extern "C" void kernel_launch(void* const* d_in, const int* in_sizes, int n_in,
                              void* d_out, int out_size, void* d_ws, size_t ws_size,
                              hipStream_t stream) {
  Bufs B;
  B.x  = (const float*)d_in[0];
  B.s0 = (const int*)d_in[1]; B.d0 = (const int*)d_in[2]; B.W0 = (const float*)d_in[3];
  B.s1 = (const int*)d_in[4]; B.d1 = (const int*)d_in[5]; B.W1 = (const float*)d_in[6];
  B.s2 = (const int*)d_in[7]; B.d2 = (const int*)d_in[8]; B.W2 = (const float*)d_in[9];
  B.aW = (const float*)d_in[10]; B.ab = (const float*)d_in[11]; B.aq = (const float*)d_in[12];
  B.out = (float*)d_out;

  char* p = (char*)d_ws;
  auto alloc = [&](size_t bytes){ char* r = p; p += (bytes + 255) & ~(size_t)255; return r; };
  // zb0, zb1, csr1 contiguous (each exactly 25.6MB, no pad) -> 76.8MB histpart overlay
  B.zb0 = (unsigned*)alloc((size_t)NN*64*4);
  B.zb1 = (unsigned*)alloc((size_t)NN*64*4);
  B.csr1 = (ushort*)alloc((size_t)NN*RNG*CAPR*2);
  B.h0  = (unsigned*)alloc((size_t)NN*64*4);
  B.h1  = (unsigned*)alloc((size_t)NN*64*4);
  B.h2  = (unsigned*)alloc((size_t)NN*64*4);
  B.csr0 = (ushort*)alloc((size_t)NN*RNG*CAPR*2);
  B.cursor = (int*)alloc(((size_t)3*NN*RNG + 4)*4);
  B.wpart  = (float*)(B.cursor + (size_t)3*NN*RNG);
  B.wblk = (float*)alloc((size_t)3*3125*4);
  B.rs  = (float*)alloc((size_t)3*NN*4);
  B.fhi = (ushort*)alloc((size_t)4*16384*2);
  B.flo = (ushort*)alloc((size_t)4*16384*2);
  B.histpart = (int*)B.zb0;    // 76.8 MB spans zb0+zb1+csr1; dead after K0b reduce
                               // (csr1 first written by bucket1 in K2)
  B.zb2 = B.h0;                // h0 dead after gather0 (K2); gather2 writes it in K4

  // K0: hist(1536) + zero(587) + prep(4)
  k0_kernel<<<8*CHK*3+587+4, 256, 0, stream>>>(B);
  // K0b: reduce histpart -> rs (tiny)
  reduce_kernel<<<(3*NN+255)/256, 256, 0, stream>>>(B);
  // K1: bucket0 || gemm0 x3 (rs-scaled epilogue)
  megaA<<<3125+9375, 256, 0, stream>>>(B);
  // K2: gather0->zb0 || bucket1
  megaGB<<<25000+3125, 256, 0, stream>>>(B, 0, 1);
  // K3: gather1->zb1 || bucket2
  megaGB<<<25000+3125, 256, 0, stream>>>(B, 1, 2);
  // K4: gather2->zb2 alone (low-VGPR kernel)
  megaG<<<25000, 256, 0, stream>>>(B);
  // K5: g1b x3 (block partials, no atomics)
  megaC<<<3125+3125+3125, 256, 0, stream>>>(B);
  // K5b: wreduce -> wpart
  wreduce_kernel<<<3, 256, 0, stream>>>(B);
  // K6: combine (writes all of out)
  combine_kernel<<<(NN*64)/256, 256, 0, stream>>>(B);
}

// Round 20
// 762.472 us; speedup vs baseline: 1.0035x; 1.0035x over previous
//
#include <hip/hip_runtime.h>
#include <hip/hip_bf16.h>

#define NN 100000
#define EE 1600000
#define DD 128
#define RNG 8        // src ranges for gather L2 locality
#define RSZ 12500    // nodes per range
#define CAPR 16      // csr slots per (node, range)
#define CHK 64       // edge chunks for histogram (1536 blocks = 256 CUs x 6)

typedef __attribute__((ext_vector_type(8))) short bf16x8;
typedef __attribute__((ext_vector_type(4))) float f32x4;
union FB { unsigned u[4]; uint4 u4; bf16x8 v; };

__device__ inline unsigned f2bf(float x){unsigned u=__float_as_uint(x);return (u+0x7fffu+((u>>16)&1u))>>16;}
__device__ inline unsigned bf16pack(float a,float b){return (f2bf(b)<<16)|(f2bf(a)&0xffffu);}
__device__ inline unsigned packsplit(float v){unsigned hb=f2bf(v);float hf=__uint_as_float(hb<<16);unsigned lb=f2bf(v-hf);return (hb<<16)|(lb&0xffffu);}
__device__ inline float bflo(unsigned u){return __uint_as_float(u<<16);}
__device__ inline float bfhi(unsigned u){return __uint_as_float(u&0xffff0000u);}

struct Bufs {
  const float* x;
  const int *s0,*d0,*s1,*d1,*s2,*d2;
  const float *W0,*W1,*W2,*aW,*ab,*aq;
  unsigned *h0,*h1,*h2;      // bf16 h per relation (rs-scaled in gemm0 epilogue)
  unsigned *zb0,*zb1,*zb2;   // bf16 z, h-layout; zb2 overlays h0 (dead after K2)
  ushort *csr0,*csr1;        // csr2 reuses csr0
  int *cursor;               // 3*NN*RNG (+wpart tail)
  float *wpart;              // 4 floats
  float *wblk;               // 3*625 block partials (no atomics)
  float *rs;                 // 3*NN rsqrt(max(deg_out,1))
  int *histpart;             // overlay on zb0+zb1+csr1 (76.8MB, dead after K0b)
  ushort *fhi,*flo;
  float *out;
};

// ================= K0: hist + zero + prep =================
__global__ __launch_bounds__(256) void k0_kernel(Bufs B) {
  __shared__ unsigned bins[RSZ/2];   // 25 KB
  int b = blockIdx.x;
  if (b < 8*CHK*3) {                 // deg_out hist partials, LDS-privatized
    int range = b & 7, chunk = (b >> 3) & (CHK-1), rel = b >> 9;
    const int* src = rel==0?B.s0: rel==1?B.s1:B.s2;
    for (int i=threadIdx.x;i<RSZ/2;i+=256) bins[i]=0;
    __syncthreads();
    int lo = range*RSZ, e0 = chunk*(EE/CHK);
    for (int e=e0+(int)threadIdx.x; e<e0+EE/CHK; e+=256){
      int v = src[e]-lo;
      if ((unsigned)v<(unsigned)RSZ) atomicAdd(&bins[v>>1], 1u<<((v&1)*16));
    }
    __syncthreads();
    int* outp = B.histpart + ((size_t)(rel*CHK+chunk))*NN + lo;
    for (int i=threadIdx.x;i<RSZ;i+=256) outp[i] = (bins[i>>1]>>((i&1)*16)) & 0xffff;
  } else if (b < 8*CHK*3+587) {      // zero cursors + wpart
    int id = b-8*CHK*3;
    const int Z = 3*NN*RNG + 4;
    int* dst = B.cursor;
#pragma unroll
    for (int k=0;k<4;++k){
      int off = id*4096 + k*1024 + (int)threadIdx.x*4;
      if (off+4 <= Z) *(int4*)(dst+off) = make_int4(0,0,0,0);
      else { for (int j=0;j<4;++j) if (off+j<Z) dst[off+j]=0; }
    }
  } else {                           // prep: W^T hi/lo MFMA fragments
    int m = b - (8*CHK*3+587);
    const float* W = m==0?B.W0: m==1?B.W1: m==2?B.W2: B.aW;
    ushort* ho = B.fhi + (size_t)m*16384;
    ushort* lp = B.flo + (size_t)m*16384;
    for (int idx=threadIdx.x; idx<16384; idx+=256){
      int j=idx&7, lane=(idx>>3)&63, ft=(idx>>9)&7, ks=idx>>12;
      int k = ks*32 + (lane>>4)*8 + j;
      int f = ft*16 + (lane&15);
      float v = W[k*128+f];
      unsigned hb = f2bf(v);
      float hf = __uint_as_float(hb<<16);
      ho[idx]=(ushort)hb; lp[idx]=(ushort)f2bf(v-hf);
    }
  }
}

// ================= K0b: reduce histpart -> rs =================
__global__ __launch_bounds__(256) void reduce_kernel(Bufs B) {
  int tid = blockIdx.x*256 + threadIdx.x;
  if (tid >= 3*NN) return;
  int rel = tid/NN, n = tid-rel*NN;
  const int* p = B.histpart + (size_t)rel*CHK*NN + n;
  int s = 0;
#pragma unroll 16
  for (int c=0;c<CHK;++c) s += p[(size_t)c*NN];
  B.rs[tid] = rsqrtf(fmaxf((float)s, 1.f));
}

// ================= jobs =================
__device__ inline void do_bucket(int id, int rel, const Bufs& B) {
  const int* src = rel==0?B.s0: rel==1?B.s1:B.s2;
  const int* dst = rel==0?B.d0: rel==1?B.d1:B.d2;
  int* cur = B.cursor + (size_t)rel*NN*RNG;
  ushort* csr = (rel==1)? B.csr1 : B.csr0;
  int e0 = id*512;
  for (int e=e0+(int)threadIdx.x; e<e0+512; e+=256){
    int s = src[e], d = dst[e];
    int rg = s / RSZ;
    int pos = atomicAdd(&cur[d*RNG+rg], 1);
    if (pos < CAPR) csr[((size_t)d*RNG+rg)*CAPR + pos] = (ushort)(s - rg*RSZ);
  }
}

// h = (x @ W) * rs  (bf16 packed out), split hi/lo 3-pass MFMA
__device__ inline void do_gemm0(int tile, int rel, const Bufs& B, unsigned (*As)[132]) {
  const uint4* Bhi = (const uint4*)(B.fhi + (size_t)rel*16384);
  const uint4* Blo = (const uint4*)(B.flo + (size_t)rel*16384);
  unsigned* h = rel==0?B.h0: rel==1?B.h1:B.h2;
  int t = threadIdx.x, row0 = tile*32;
  for (int idx=t; idx<32*32; idx+=256){
    int r = idx>>5, c4 = (idx&31)<<2;
    float4 v = *(const float4*)(B.x + (size_t)(row0+r)*DD + c4);
    uint4 pk; pk.x=packsplit(v.x); pk.y=packsplit(v.y); pk.z=packsplit(v.z); pk.w=packsplit(v.w);
    *(uint4*)&As[r][c4] = pk;
  }
  __syncthreads();
  int wv=t>>6, l=t&63, ln=l&15, lk=l>>4;
  int nrow=(wv&1)*16+ln, fh=wv>>1;
  f32x4 acc[4];
#pragma unroll
  for (int i=0;i<4;++i) acc[i] = (f32x4){0.f,0.f,0.f,0.f};
#pragma unroll
  for (int ks=0;ks<4;++ks){
    unsigned u[8];
    int kd = ks*32 + lk*8;
    *(uint4*)&u[0] = *(const uint4*)&As[nrow][kd];
    *(uint4*)&u[4] = *(const uint4*)&As[nrow][kd+4];
    FB bh, bl;
#pragma unroll
    for (int i=0;i<4;++i){
      bh.u[i] = (u[2*i]>>16) | (u[2*i+1]&0xffff0000u);
      bl.u[i] = (u[2*i]&0xffffu) | (u[2*i+1]<<16);
    }
#pragma unroll
    for (int fi=0;fi<4;++fi){
      int ft = fh*4+fi;
      FB wh, wl;
      wh.u4 = Bhi[(ks*8+ft)*64 + l];
      wl.u4 = Blo[(ks*8+ft)*64 + l];
      acc[fi] = __builtin_amdgcn_mfma_f32_16x16x32_bf16(wh.v, bh.v, acc[fi],0,0,0);
      acc[fi] = __builtin_amdgcn_mfma_f32_16x16x32_bf16(wl.v, bh.v, acc[fi],0,0,0);
      acc[fi] = __builtin_amdgcn_mfma_f32_16x16x32_bf16(wh.v, bl.v, acc[fi],0,0,0);
    }
  }
  int node = row0+nrow;
  float sc = B.rs[rel*NN + node];
#pragma unroll
  for (int fi=0;fi<4;++fi){
    int ft = fh*4+fi;
    uint2 o;
    o.x = bf16pack(acc[fi][0]*sc, acc[fi][1]*sc);
    o.y = bf16pack(acc[fi][2]*sc, acc[fi][3]*sc);
    *(uint2*)(h + (size_t)node*64 + ft*8 + lk*2) = o;
  }
}

// gather (R6 shape): 1 node/wave, 4 nodes/block; slot-major over 8 ranges
// for ~8-deep load ILP; h pre-scaled. All rels write bf16 zb.
__device__ inline void do_gather(int id, int rel, const Bufs& B) {
  int node = id*4 + (threadIdx.x>>6);
  int lane = threadIdx.x & 63;
  const int* cur = B.cursor + (size_t)rel*NN*RNG + (size_t)node*RNG;
  const ushort* csr = (rel==1)? B.csr1 : B.csr0;
  const unsigned* h = rel==0?B.h0: rel==1?B.h1:B.h2;
  int cnt[RNG];
  int deg = 0, maxc = 0;
#pragma unroll
  for (int k=0;k<RNG;++k){
    int c = cur[k];
    deg += c;
    c = min(c, CAPR);
    cnt[k] = c;
    maxc = max(maxc, c);
  }
  const ushort* base = csr + (size_t)node*(RNG*CAPR);
  float ax = 0.f, ay = 0.f;
  for (int s=0;s<maxc;++s){
    unsigned u[RNG];
#pragma unroll
    for (int k=0;k<RNG;++k){
      if (s < cnt[k]){
        int idx = k*RSZ + (int)base[k*CAPR + s];
        u[k] = h[(size_t)idx*64 + lane];
      }
    }
#pragma unroll
    for (int k=0;k<RNG;++k){
      if (s < cnt[k]){ ax += bflo(u[k]); ay += bfhi(u[k]); }
    }
  }
  float sc = rsqrtf(fmaxf((float)deg, 1.f));
  unsigned* zb = rel==0?B.zb0: rel==1?B.zb1:B.zb2;
  zb[(size_t)node*64+lane] = bf16pack(ax*sc, ay*sc);
}

// g1b5: semantic GEMM over 5 tiles (160 nodes) per block — fragment pairs are
// loaded once per (ks,ft) and reused across the 5 tiles (frag traffic /5).
// Block partial -> wblk[rel*625 + tile5] (plain store, no atomics).
__device__ inline void do_g1b5(int tile5, int rel, const Bufs& B,
                               unsigned (*As)[68], float* red) {
  const unsigned* zb = rel==0?B.zb0: rel==1?B.zb1:B.zb2;
  const uint4* Bhi = (const uint4*)(B.fhi + (size_t)3*16384);
  const uint4* Blo = (const uint4*)(B.flo + (size_t)3*16384);
  int t = threadIdx.x, row0 = tile5*160;
  for (int idx=t; idx<160*16; idx+=256){
    int r = idx>>4, c4 = (idx&15)<<2;
    *(uint4*)&As[r][c4] = *(const uint4*)(zb + (size_t)(row0+r)*64 + c4);
  }
  __syncthreads();
  int wv=t>>6, l=t&63, ln=l&15, lk=l>>4;
  int nrow=(wv&1)*16+ln, fh=wv>>1;
  f32x4 acc[5][4];
#pragma unroll
  for (int T=0;T<5;++T)
#pragma unroll
    for (int i=0;i<4;++i) acc[T][i] = (f32x4){0.f,0.f,0.f,0.f};
#pragma unroll
  for (int ks=0;ks<4;++ks){
#pragma unroll
    for (int fi=0;fi<4;++fi){
      int ft = fh*4+fi;
      FB wh, wl;
      wh.u4 = Bhi[(ks*8+ft)*64 + l];
      wl.u4 = Blo[(ks*8+ft)*64 + l];
#pragma unroll
      for (int T=0;T<5;++T){
        FB bb; bb.u4 = *(const uint4*)&As[T*32+nrow][ks*16 + lk*4];
        acc[T][fi] = __builtin_amdgcn_mfma_f32_16x16x32_bf16(wh.v, bb.v, acc[T][fi],0,0,0);
        acc[T][fi] = __builtin_amdgcn_mfma_f32_16x16x32_bf16(wl.v, bb.v, acc[T][fi],0,0,0);
      }
    }
  }
  float s = 0.f;
#pragma unroll
  for (int T=0;T<5;++T){
#pragma unroll
    for (int fi=0;fi<4;++fi){
#pragma unroll
      for (int r=0;r<4;++r){
        int f = (fh*4+fi)*16 + lk*4 + r;
        float v = acc[T][fi][r] + B.ab[f];
        float e = __expf(2.f*v);
        s += (1.f - 2.f/(e+1.f)) * B.aq[f];
      }
    }
  }
#pragma unroll
  for (int m=1;m<64;m<<=1) s += __shfl_xor(s, m);
  if (l==0) red[wv] = s;
  __syncthreads();
  if (t==0) B.wblk[rel*625 + tile5] = red[0]+red[1]+red[2]+red[3];
}

// ===== specialized dispatchers =====

// K1: bucket0(3125) || gemm0 x3(9375)
__global__ __launch_bounds__(256) void megaA(Bufs B) {
  __shared__ unsigned As[32][132];
  const int n0=3125, n1=9375;
  const int tot = n0+n1;
  int b = blockIdx.x;
  long f = ((long)b*n0)/tot;
  if (((long)(b+1)*n0)/tot > f){ do_bucket((int)f, 0, B); return; }
  int g = b-(int)f;
  do_gemm0(g%3125, g/3125, B, As);
}

// K2/K3: gather(25000) || bucket(3125) — 0 LDS, low VGPR
__global__ __launch_bounds__(256) void megaGB(Bufs B, int grel, int brel) {
  const int n0=25000, n1=3125;
  const int tot = n0+n1;
  int b = blockIdx.x;
  long f = ((long)b*n0)/tot;
  if (((long)(b+1)*n0)/tot > f) do_gather((int)f, grel, B);
  else                          do_bucket(b-(int)f, brel, B);
}

// K4: gather2 alone — 0 LDS, low VGPR
__global__ __launch_bounds__(256) void megaG(Bufs B) {
  do_gather(blockIdx.x, 2, B);
}

// K5: g1b5 x3 (1875 blocks; solo launch, frag-reuse x5)
__global__ __launch_bounds__(256) void megaC(Bufs B) {
  __shared__ unsigned As[160][68];   // 43.5 KB
  __shared__ float red[4];
  int b = blockIdx.x;
  int rel = b / 625;
  do_g1b5(b - rel*625, rel, B, As, red);
}

// K5b: wreduce — 3 blocks, each sums 625 block partials -> wpart[rel]
__global__ __launch_bounds__(256) void wreduce_kernel(Bufs B) {
  __shared__ float red[4];
  int rel = blockIdx.x;
  const float* p = B.wblk + rel*625;
  float s = 0.f;
  for (int i = threadIdx.x; i < 625; i += 256) s += p[i];
#pragma unroll
  for (int m=1;m<64;m<<=1) s += __shfl_xor(s, m);
  int wv = threadIdx.x>>6, l = threadIdx.x&63;
  if (l==0) red[wv] = s;
  __syncthreads();
  if (threadIdx.x==0) B.wpart[rel] = red[0]+red[1]+red[2]+red[3];
}

// ============ combine: out = b0*zb0 + b1*zb1 + b2*zb2 (f32 out) ============
__global__ __launch_bounds__(256) void combine_kernel(Bufs B) {
  int tid = blockIdx.x*256 + threadIdx.x;   // < NN*64
  float w0 = B.wpart[0]*(1.f/NN), w1 = B.wpart[1]*(1.f/NN), w2 = B.wpart[2]*(1.f/NN);
  float m = fmaxf(w0, fmaxf(w1,w2));
  float e0 = expf(w0-m), e1 = expf(w1-m), e2 = expf(w2-m);
  float inv = 1.f/(e0+e1+e2);
  float b0 = e0*inv, b1 = e1*inv, b2 = e2*inv;
  unsigned u0 = B.zb0[tid], u1 = B.zb1[tid], u2 = B.zb2[tid];
  float2 o;
  o.x = b0*bflo(u0) + b1*bflo(u1) + b2*bflo(u2);
  o.y = b0*bfhi(u0) + b1*bfhi(u1) + b2*bfhi(u2);
  ((float2*)B.out)[tid] = o;
}

extern "C" void kernel_launch(void* const* d_in, const int* in_sizes, int n_in,
                              void* d_out, int out_size, void* d_ws, size_t ws_size,
                              hipStream_t stream) {
  Bufs B;
  B.x  = (const float*)d_in[0];
  B.s0 = (const int*)d_in[1]; B.d0 = (const int*)d_in[2]; B.W0 = (const float*)d_in[3];
  B.s1 = (const int*)d_in[4]; B.d1 = (const int*)d_in[5]; B.W1 = (const float*)d_in[6];
  B.s2 = (const int*)d_in[7]; B.d2 = (const int*)d_in[8]; B.W2 = (const float*)d_in[9];
  B.aW = (const float*)d_in[10]; B.ab = (const float*)d_in[11]; B.aq = (const float*)d_in[12];
  B.out = (float*)d_out;

  char* p = (char*)d_ws;
  auto alloc = [&](size_t bytes){ char* r = p; p += (bytes + 255) & ~(size_t)255; return r; };
  // zb0, zb1, csr1 contiguous (each exactly 25.6MB, no pad) -> 76.8MB histpart overlay
  B.zb0 = (unsigned*)alloc((size_t)NN*64*4);
  B.zb1 = (unsigned*)alloc((size_t)NN*64*4);
  B.csr1 = (ushort*)alloc((size_t)NN*RNG*CAPR*2);
  B.h0  = (unsigned*)alloc((size_t)NN*64*4);
  B.h1  = (unsigned*)alloc((size_t)NN*64*4);
  B.h2  = (unsigned*)alloc((size_t)NN*64*4);
  B.csr0 = (ushort*)alloc((size_t)NN*RNG*CAPR*2);
  B.cursor = (int*)alloc(((size_t)3*NN*RNG + 4)*4);
  B.wpart  = (float*)(B.cursor + (size_t)3*NN*RNG);
  B.wblk = (float*)alloc((size_t)3*625*4);
  B.rs  = (float*)alloc((size_t)3*NN*4);
  B.fhi = (ushort*)alloc((size_t)4*16384*2);
  B.flo = (ushort*)alloc((size_t)4*16384*2);
  B.histpart = (int*)B.zb0;    // 76.8 MB spans zb0+zb1+csr1; dead after K0b reduce
                               // (csr1 first written by bucket1 in K2)
  B.zb2 = B.h0;                // h0 dead after gather0 (K2); gather2 writes it in K4

  // K0: hist(1536) + zero(587) + prep(4)
  k0_kernel<<<8*CHK*3+587+4, 256, 0, stream>>>(B);
  // K0b: reduce histpart -> rs (tiny)
  reduce_kernel<<<(3*NN+255)/256, 256, 0, stream>>>(B);
  // K1: bucket0 || gemm0 x3 (rs-scaled epilogue)
  megaA<<<3125+9375, 256, 0, stream>>>(B);
  // K2: gather0->zb0 || bucket1
  megaGB<<<25000+3125, 256, 0, stream>>>(B, 0, 1);
  // K3: gather1->zb1 || bucket2
  megaGB<<<25000+3125, 256, 0, stream>>>(B, 1, 2);
  // K4: gather2->zb2 alone (low-VGPR kernel)
  megaG<<<25000, 256, 0, stream>>>(B);
  // K5: g1b5 x3 (frag-reuse, block partials, no atomics)
  megaC<<<3*625, 256, 0, stream>>>(B);
  // K5b: wreduce -> wpart
  wreduce_kernel<<<3, 256, 0, stream>>>(B);
  // K6: combine (writes all of out)
  combine_kernel<<<(NN*64)/256, 256, 0, stream>>>(B);
}